// Round 1
// baseline (613.066 us; speedup 1.0000x reference)
//
#include <hip/hip_runtime.h>
#include <hip/hip_bf16.h>

#define NB 64      // batch
#define NT 64      // time
#define NA 64      // action dim
#define NH 1024    // hidden
#define NE 32      // embodiments
#define K2DIM 2048 // 2H

typedef unsigned short bf16_t;

__device__ __forceinline__ float bf16_lo(unsigned int u) {
    return __uint_as_float(u << 16);
}
__device__ __forceinline__ float bf16_hi(unsigned int u) {
    return __uint_as_float(u & 0xFFFF0000u);
}
__device__ __forceinline__ bf16_t f32_to_bf16(float f) {
    unsigned int u = __float_as_uint(f);
    u = (u + 0x7FFFu + ((u >> 16) & 1u)) >> 16;   // round-to-nearest-even
    return (bf16_t)u;
}

// ---------------------------------------------------------------------------
// K1: a_emb = actions @ W1[cat] + b1  (K=64)  and sinusoidal PE, fused.
// Writes x = concat(a_emb, pe) as bf16 [B][T][2H].
// grid (B, H/64), block 256.
// ---------------------------------------------------------------------------
__global__ __launch_bounds__(256) void k1_embed(
    const float* __restrict__ actions, const float* __restrict__ W1,
    const float* __restrict__ b1, const int* __restrict__ timesteps,
    const int* __restrict__ cat_ids, bf16_t* __restrict__ x)
{
    __shared__ float act[NT][NA];
    __shared__ float pe[64];

    const int b   = blockIdx.x;
    const int c0  = blockIdx.y * 64;
    const int tid = threadIdx.x;
    const int cat = cat_ids[b];
    const float ts = (float)timesteps[b];

    const float* ab = actions + b * (NT * NA);
    #pragma unroll
    for (int p = 0; p < 16; ++p) {
        int idx = tid + p * 256;
        act[idx >> 6][idx & 63] = ab[idx];
    }
    if (tid < 64) {
        const float kfreq = logf(10000.0f) / 512.0f;
        int c = c0 + tid;
        float v;
        if (c < 512) v = sinf(ts * expf(-(float)c * kfreq));
        else         v = cosf(ts * expf(-(float)(c - 512) * kfreq));
        pe[tid] = v;
    }
    __syncthreads();

    const int cc = tid & 63;
    const int c  = c0 + cc;
    const int t0 = tid >> 6;             // 0..3 (wave-uniform)

    float acc[16];
    const float bias = b1[cat * NH + c];
    #pragma unroll
    for (int i = 0; i < 16; ++i) acc[i] = bias;

    const float* Wp = W1 + (size_t)cat * (NA * NH) + c;
    #pragma unroll 8
    for (int k = 0; k < NA; ++k) {
        float w = Wp[(size_t)k * NH];
        #pragma unroll
        for (int i = 0; i < 16; ++i)
            acc[i] = fmaf(act[t0 + 4 * i][k], w, acc[i]);
    }

    bf16_t* xb = x + (size_t)b * (NT * K2DIM);
    const bf16_t pv = f32_to_bf16(pe[cc]);
    #pragma unroll
    for (int i = 0; i < 16; ++i) {
        int t = t0 + 4 * i;
        xb[(size_t)t * K2DIM + c]      = f32_to_bf16(acc[i]);
        xb[(size_t)t * K2DIM + NH + c] = pv;
    }
}

// ---------------------------------------------------------------------------
// Generic per-batch GEMM: out[b,t,n] = xin[b,t,:] @ W[cat] + bias[cat]
// xin bf16 [B][T][KDIM], W f32 [E][KDIM][H] (k-major, n contiguous).
// Optional swish. OutT = bf16_t (pack) or float (float4 store).
// grid (B, H/128), block 256; thread computes 8t x 4n.
// ---------------------------------------------------------------------------
template<int KDIM, bool SWISH, typename OutT>
__global__ __launch_bounds__(256) void gemm_cat(
    const bf16_t* __restrict__ xin, const float* __restrict__ W,
    const float* __restrict__ bias, const int* __restrict__ cat_ids,
    OutT* __restrict__ out)
{
    __shared__ bf16_t xs[NT][64];     // 8 KB K-chunk of x

    const int b   = blockIdx.x;
    const int n0  = blockIdx.y * 128;
    const int tid = threadIdx.x;
    const int cat = cat_ids[b];

    const int n  = n0 + (tid & 31) * 4;
    const int t0 = (tid >> 5) * 8;    // 2 t-groups per wave -> 2-way LDS bcast (free)

    float acc[8][4];
    const float4 bv = *(const float4*)(bias + (size_t)cat * NH + n);
    #pragma unroll
    for (int i = 0; i < 8; ++i) {
        acc[i][0] = bv.x; acc[i][1] = bv.y; acc[i][2] = bv.z; acc[i][3] = bv.w;
    }

    const bf16_t* xb = xin + (size_t)b * (NT * KDIM);
    const float*  Wb = W + (size_t)cat * KDIM * NH;

    for (int kc = 0; kc < KDIM / 64; ++kc) {
        // stage x chunk [64t][64k] as uint4 (8 bf16) coalesced
        #pragma unroll
        for (int p = 0; p < 2; ++p) {
            int id = tid + p * 256;           // 0..511
            int t  = id >> 3;
            int c8 = (id & 7) * 8;
            *(uint4*)&xs[t][c8] = *(const uint4*)(xb + (size_t)t * KDIM + kc * 64 + c8);
        }
        __syncthreads();

        const float* Wp = Wb + (size_t)(kc * 64) * NH + n;
        #pragma unroll 4
        for (int kk = 0; kk < 64; kk += 2) {
            const float4 w0 = *(const float4*)(Wp + (size_t)kk * NH);
            const float4 w1 = *(const float4*)(Wp + (size_t)(kk + 1) * NH);
            #pragma unroll
            for (int i = 0; i < 8; ++i) {
                unsigned int u = *(const unsigned int*)(&xs[t0 + i][kk]);
                float x0 = bf16_lo(u);
                float x1 = bf16_hi(u);
                acc[i][0] = fmaf(x0, w0.x, acc[i][0]);
                acc[i][1] = fmaf(x0, w0.y, acc[i][1]);
                acc[i][2] = fmaf(x0, w0.z, acc[i][2]);
                acc[i][3] = fmaf(x0, w0.w, acc[i][3]);
                acc[i][0] = fmaf(x1, w1.x, acc[i][0]);
                acc[i][1] = fmaf(x1, w1.y, acc[i][1]);
                acc[i][2] = fmaf(x1, w1.z, acc[i][2]);
                acc[i][3] = fmaf(x1, w1.w, acc[i][3]);
            }
        }
        __syncthreads();
    }

    OutT* ob = out + (size_t)b * (NT * NH);
    #pragma unroll
    for (int i = 0; i < 8; ++i) {
        int t = t0 + i;
        float r[4];
        #pragma unroll
        for (int j = 0; j < 4; ++j) {
            float h = acc[i][j];
            if (SWISH) h = h / (1.0f + expf(-h));
            r[j] = h;
        }
        if constexpr (sizeof(OutT) == 2) {
            uint2 pk;
            pk.x = (unsigned int)f32_to_bf16(r[0]) | ((unsigned int)f32_to_bf16(r[1]) << 16);
            pk.y = (unsigned int)f32_to_bf16(r[2]) | ((unsigned int)f32_to_bf16(r[3]) << 16);
            *(uint2*)(ob + (size_t)t * NH + n) = pk;
        } else {
            float4 st;
            st.x = r[0]; st.y = r[1]; st.z = r[2]; st.w = r[3];
            *(float4*)(ob + (size_t)t * NH + n) = st;
        }
    }
}

extern "C" void kernel_launch(void* const* d_in, const int* in_sizes, int n_in,
                              void* d_out, int out_size, void* d_ws, size_t ws_size,
                              hipStream_t stream) {
    const float* actions   = (const float*)d_in[0];
    const float* W1        = (const float*)d_in[1];
    const float* b1        = (const float*)d_in[2];
    const float* W2        = (const float*)d_in[3];
    const float* b2        = (const float*)d_in[4];
    const float* W3        = (const float*)d_in[5];
    const float* b3        = (const float*)d_in[6];
    const int*   timesteps = (const int*)d_in[7];
    const int*   cat_ids   = (const int*)d_in[8];
    float* out = (float*)d_out;

    // ws: x bf16 [B][T][2H] (16 MB) then y bf16 [B][T][H] (8 MB)
    bf16_t* x = (bf16_t*)d_ws;
    bf16_t* y = x + (size_t)NB * NT * K2DIM;

    k1_embed<<<dim3(NB, NH / 64), 256, 0, stream>>>(actions, W1, b1, timesteps, cat_ids, x);
    gemm_cat<K2DIM, true,  bf16_t><<<dim3(NB, NH / 128), 256, 0, stream>>>(x, W2, b2, cat_ids, y);
    gemm_cat<NH,    false, float ><<<dim3(NB, NH / 128), 256, 0, stream>>>(y, W3, b3, cat_ids, out);
}

// Round 2
// 179.063 us; speedup vs baseline: 3.4237x; 3.4237x over previous
//
#include <hip/hip_runtime.h>
#include <hip/hip_bf16.h>

#define NB 64      // batch
#define NT 64      // time
#define NA 64      // action dim
#define NH 1024    // hidden
#define NE 32      // embodiments
#define K2DIM 2048 // 2H

typedef unsigned short bf16_t;
typedef __attribute__((ext_vector_type(8))) short bf16x8;  // 8 bf16 = 4 VGPRs
typedef __attribute__((ext_vector_type(4))) float f32x4;   // MFMA accumulator

__device__ __forceinline__ float bf16_lo(unsigned int u) {
    return __uint_as_float(u << 16);
}
__device__ __forceinline__ float bf16_hi(unsigned int u) {
    return __uint_as_float(u & 0xFFFF0000u);
}
__device__ __forceinline__ bf16_t f32_to_bf16(float f) {
    unsigned int u = __float_as_uint(f);
    u = (u + 0x7FFFu + ((u >> 16) & 1u)) >> 16;   // round-to-nearest-even
    return (bf16_t)u;
}
__device__ __forceinline__ unsigned int pack_bf16x2(float lo, float hi) {
    return (unsigned int)f32_to_bf16(lo) | ((unsigned int)f32_to_bf16(hi) << 16);
}

// ---------------------------------------------------------------------------
// K1: a_emb = actions @ W1[cat] + b1  (K=64)  and sinusoidal PE, fused.
// Writes x = concat(a_emb, pe) as bf16 [B][T][2H] (linear layout).
// grid (B, H/64), block 256.  (unchanged from round 1 — it's ~1% of time)
// ---------------------------------------------------------------------------
__global__ __launch_bounds__(256) void k1_embed(
    const float* __restrict__ actions, const float* __restrict__ W1,
    const float* __restrict__ b1, const int* __restrict__ timesteps,
    const int* __restrict__ cat_ids, bf16_t* __restrict__ x)
{
    __shared__ float act[NT][NA];
    __shared__ float pe[64];

    const int b   = blockIdx.x;
    const int c0  = blockIdx.y * 64;
    const int tid = threadIdx.x;
    const int cat = cat_ids[b];
    const float ts = (float)timesteps[b];

    const float* ab = actions + b * (NT * NA);
    #pragma unroll
    for (int p = 0; p < 16; ++p) {
        int idx = tid + p * 256;
        act[idx >> 6][idx & 63] = ab[idx];
    }
    if (tid < 64) {
        const float kfreq = logf(10000.0f) / 512.0f;
        int c = c0 + tid;
        float v;
        if (c < 512) v = sinf(ts * expf(-(float)c * kfreq));
        else         v = cosf(ts * expf(-(float)(c - 512) * kfreq));
        pe[tid] = v;
    }
    __syncthreads();

    const int cc = tid & 63;
    const int c  = c0 + cc;
    const int t0 = tid >> 6;             // 0..3 (wave-uniform)

    float acc[16];
    const float bias = b1[cat * NH + c];
    #pragma unroll
    for (int i = 0; i < 16; ++i) acc[i] = bias;

    const float* Wp = W1 + (size_t)cat * (NA * NH) + c;
    #pragma unroll 8
    for (int k = 0; k < NA; ++k) {
        float w = Wp[(size_t)k * NH];
        #pragma unroll
        for (int i = 0; i < 16; ++i)
            acc[i] = fmaf(act[t0 + 4 * i][k], w, acc[i]);
    }

    bf16_t* xb = x + (size_t)b * (NT * K2DIM);
    const bf16_t pv = f32_to_bf16(pe[cc]);
    #pragma unroll
    for (int i = 0; i < 16; ++i) {
        int t = t0 + 4 * i;
        xb[(size_t)t * K2DIM + c]      = f32_to_bf16(acc[i]);
        xb[(size_t)t * K2DIM + NH + c] = pv;
    }
}

// ---------------------------------------------------------------------------
// MFMA GEMM: out[b,t,n] = xin[b,t,:] @ W[cat] + bias[cat]  (+ optional swish)
// xin bf16 [B][T][KDIM]; W f32 [E][KDIM][NH] (n contiguous); out [B][T][NH].
// grid (B, NH/64), block 256 (4 waves). Each wave: 32x32 sub-tile = 2x2
// mfma_f32_16x16x32_bf16 frags. Per 64-k chunk:
//   xs  [64t][64k] bf16, XOR-swizzled (byte ^= (t&7)<<4)      — A operand
//   wsm [64n][64k] bf16, TRANSPOSED + XOR-swizzled            — B operand
// W staged via f32 loads + cvt + k-pair-packed ds_write_b32.
// Fragment reads are ds_read_b128, conflict-free under the swizzle (G4).
// ---------------------------------------------------------------------------
template<int KDIM, bool SWISH, typename OutT>
__global__ __launch_bounds__(256, 4) void gemm_mfma(
    const bf16_t* __restrict__ xin, const float* __restrict__ W,
    const float* __restrict__ bias, const int* __restrict__ cat_ids,
    OutT* __restrict__ out)
{
    __shared__ char xs[64 * 128];   // 8 KB
    __shared__ char wsm[64 * 128];  // 8 KB

    const int b    = blockIdx.x;
    const int n0   = blockIdx.y * 64;
    const int tid  = threadIdx.x;
    const int lane = tid & 63;
    const int wv   = tid >> 6;           // wave 0..3
    const int cat  = cat_ids[b];

    const int mw = (wv & 1) * 32;        // wave m (t) offset
    const int nw = (wv >> 1) * 32;       // wave n offset within 64-tile
    const int l15 = lane & 15;
    const int l4  = lane >> 4;

    const bf16_t* xb = xin + (size_t)b * (size_t)NT * KDIM;
    const float*  Wb = W + (size_t)cat * KDIM * NH + n0;

    f32x4 acc[2][2];
    #pragma unroll
    for (int m = 0; m < 2; ++m)
        #pragma unroll
        for (int n = 0; n < 2; ++n) {
            float bv = bias[(size_t)cat * NH + n0 + nw + n * 16 + l15];
            acc[m][n] = (f32x4){bv, bv, bv, bv};
        }

    const int nn   = lane;               // W staging: n index 0..63
    const int wswz = (nn & 7) << 4;

    for (int kc = 0; kc < KDIM / 64; ++kc) {
        const bf16_t* xsrc = xb + kc * 64;
        const float*  Wp   = Wb + (size_t)(kc * 64) * NH;

        __syncthreads();   // prior-iter LDS reads done before overwrite

        // stage x chunk: 512 uint4 = [64t][8 k-groups of 8 bf16]
        #pragma unroll
        for (int p = 0; p < 2; ++p) {
            int id = tid + p * 256;
            int t  = id >> 3;
            int k8 = id & 7;
            uint4 v = *(const uint4*)(xsrc + (size_t)t * KDIM + k8 * 8);
            int off = (t * 128 + k8 * 16) ^ ((t & 7) << 4);
            *(uint4*)(xs + off) = v;
        }
        // stage W chunk transposed: per pass, wave wv covers k-pair rows
        #pragma unroll
        for (int p = 0; p < 8; ++p) {
            int k0 = 2 * (p * 4 + wv);   // even k
            float a0 = Wp[(size_t)k0 * NH + nn];
            float a1 = Wp[(size_t)(k0 + 1) * NH + nn];
            unsigned int pk = pack_bf16x2(a0, a1);
            int off = (nn * 128 + k0 * 2) ^ wswz;
            *(unsigned int*)(wsm + off) = pk;
        }
        __syncthreads();

        #pragma unroll
        for (int ks = 0; ks < 2; ++ks) {
            bf16x8 af[2], bfr[2];
            #pragma unroll
            for (int m = 0; m < 2; ++m) {
                int row = mw + m * 16 + l15;
                int off = (row * 128 + ks * 64 + l4 * 16) ^ ((row & 7) << 4);
                af[m] = *(const bf16x8*)(xs + off);
            }
            #pragma unroll
            for (int n = 0; n < 2; ++n) {
                int row = nw + n * 16 + l15;
                int off = (row * 128 + ks * 64 + l4 * 16) ^ ((row & 7) << 4);
                bfr[n] = *(const bf16x8*)(wsm + off);
            }
            #pragma unroll
            for (int m = 0; m < 2; ++m)
                #pragma unroll
                for (int n = 0; n < 2; ++n)
                    acc[m][n] = __builtin_amdgcn_mfma_f32_16x16x32_bf16(
                        af[m], bfr[n], acc[m][n], 0, 0, 0);
        }
    }

    // epilogue: C/D layout col = lane&15, row = (lane>>4)*4 + reg  [m89/m91]
    #pragma unroll
    for (int m = 0; m < 2; ++m) {
        #pragma unroll
        for (int n = 0; n < 2; ++n) {
            int col = n0 + nw + n * 16 + l15;
            #pragma unroll
            for (int r = 0; r < 4; ++r) {
                int row = mw + m * 16 + l4 * 4 + r;
                float h = acc[m][n][r];
                if (SWISH) h = h / (1.0f + __expf(-h));
                if constexpr (sizeof(OutT) == 2) {
                    out[((size_t)b * NT + row) * NH + col] = (OutT)f32_to_bf16(h);
                } else {
                    out[((size_t)b * NT + row) * NH + col] = h;
                }
            }
        }
    }
}

extern "C" void kernel_launch(void* const* d_in, const int* in_sizes, int n_in,
                              void* d_out, int out_size, void* d_ws, size_t ws_size,
                              hipStream_t stream) {
    const float* actions   = (const float*)d_in[0];
    const float* W1        = (const float*)d_in[1];
    const float* b1        = (const float*)d_in[2];
    const float* W2        = (const float*)d_in[3];
    const float* b2        = (const float*)d_in[4];
    const float* W3        = (const float*)d_in[5];
    const float* b3        = (const float*)d_in[6];
    const int*   timesteps = (const int*)d_in[7];
    const int*   cat_ids   = (const int*)d_in[8];
    float* out = (float*)d_out;

    // ws: x bf16 [B][T][2H] (16 MB) then y bf16 [B][T][H] (8 MB)
    bf16_t* x = (bf16_t*)d_ws;
    bf16_t* y = x + (size_t)NB * NT * K2DIM;

    k1_embed<<<dim3(NB, NH / 64), 256, 0, stream>>>(actions, W1, b1, timesteps, cat_ids, x);
    gemm_mfma<K2DIM, true,  bf16_t><<<dim3(NB, NH / 64), 256, 0, stream>>>(x, W2, b2, cat_ids, y);
    gemm_mfma<NH,    false, float ><<<dim3(NB, NH / 64), 256, 0, stream>>>(y, W3, b3, cat_ids, out);
}

// Round 3
// 157.480 us; speedup vs baseline: 3.8930x; 1.1370x over previous
//
#include <hip/hip_runtime.h>
#include <hip/hip_bf16.h>

#define NB 64      // batch
#define NT 64      // time
#define NA 64      // action dim
#define NH 1024    // hidden
#define NE 32      // embodiments
#define K2DIM 2048 // 2H

typedef unsigned short bf16_t;
typedef __attribute__((ext_vector_type(8))) short bf16x8;  // 8 bf16 = 4 VGPRs
typedef __attribute__((ext_vector_type(4))) short s16x4;   // 4 bf16 = 2 VGPRs
typedef __attribute__((ext_vector_type(4))) float f32x4;   // MFMA accumulator

__device__ __forceinline__ bf16_t f32_to_bf16(float f) {
    unsigned int u = __float_as_uint(f);
    u = (u + 0x7FFFu + ((u >> 16) & 1u)) >> 16;   // round-to-nearest-even
    return (bf16_t)u;
}
// native cvt pair (compiler emits v_cvt_pk_bf16_f32) — m240: don't hand-write asm
__device__ __forceinline__ unsigned cvt2(float x, float y) {
    unsigned short a = __builtin_bit_cast(unsigned short, __float2bfloat16(x));
    unsigned short b = __builtin_bit_cast(unsigned short, __float2bfloat16(y));
    return (unsigned)a | ((unsigned)b << 16);
}

// ---------------------------------------------------------------------------
// K1: a_emb = actions @ W1[cat] + b1 (K=64) and sinusoidal PE, fused.
// Writes x = concat(a_emb, pe) as bf16 [B][T][2H]. grid (B, H/64), block 256.
// ---------------------------------------------------------------------------
__global__ __launch_bounds__(256) void k1_embed(
    const float* __restrict__ actions, const float* __restrict__ W1,
    const float* __restrict__ b1, const int* __restrict__ timesteps,
    const int* __restrict__ cat_ids, bf16_t* __restrict__ x)
{
    __shared__ float act[NT][NA];
    __shared__ float pe[64];

    const int b   = blockIdx.x;
    const int c0  = blockIdx.y * 64;
    const int tid = threadIdx.x;
    const int cat = cat_ids[b];
    const float ts = (float)timesteps[b];

    const float* ab = actions + b * (NT * NA);
    #pragma unroll
    for (int p = 0; p < 16; ++p) {
        int idx = tid + p * 256;
        act[idx >> 6][idx & 63] = ab[idx];
    }
    if (tid < 64) {
        const float kfreq = logf(10000.0f) / 512.0f;
        int c = c0 + tid;
        float v;
        if (c < 512) v = sinf(ts * expf(-(float)c * kfreq));
        else         v = cosf(ts * expf(-(float)(c - 512) * kfreq));
        pe[tid] = v;
    }
    __syncthreads();

    const int cc = tid & 63;
    const int c  = c0 + cc;
    const int t0 = tid >> 6;

    float acc[16];
    const float bias = b1[cat * NH + c];
    #pragma unroll
    for (int i = 0; i < 16; ++i) acc[i] = bias;

    const float* Wp = W1 + (size_t)cat * (NA * NH) + c;
    #pragma unroll 8
    for (int k = 0; k < NA; ++k) {
        float w = Wp[(size_t)k * NH];
        #pragma unroll
        for (int i = 0; i < 16; ++i)
            acc[i] = fmaf(act[t0 + 4 * i][k], w, acc[i]);
    }

    bf16_t* xb = x + (size_t)b * (NT * K2DIM);
    const bf16_t pv = f32_to_bf16(pe[cc]);
    #pragma unroll
    for (int i = 0; i < 16; ++i) {
        int t = t0 + 4 * i;
        xb[(size_t)t * K2DIM + c]      = f32_to_bf16(acc[i]);
        xb[(size_t)t * K2DIM + NH + c] = pv;
    }
}

// ---------------------------------------------------------------------------
// MFMA GEMM: out[b,t,n] = xin[b,t,:] @ W[cat] + bias[cat]  (+ optional swish)
// Block tile 64t x 128n, 4 waves (2x2), each wave 32t x 64n = 2x4 16x16 frags.
// Per 64-k chunk:
//   xs:  [64t][64k] bf16, XOR swizzle (byte ^= (t&7)<<4)   — A via ds_read_b128
//   wsm: k-major subtiled [k/4][n/16][4k][16n] bf16 (tile = 128 B)
//        staged by float4 loads + v_cvt_pk + ds_write_b128
//        read as B-frags via ds_read_b64_tr_b16 (2 reads = 8 consecutive k)
// ---------------------------------------------------------------------------
template<int KDIM, bool SWISH, typename OutT>
__global__ __launch_bounds__(256, 2) void gemm_mfma(
    const bf16_t* __restrict__ xin, const float* __restrict__ W,
    const float* __restrict__ bias, const int* __restrict__ cat_ids,
    OutT* __restrict__ out)
{
    __shared__ __align__(128) char xs[64 * 128];   // 8 KB
    __shared__ __align__(128) char wsm[16384];     // 16 KB

    const int b    = blockIdx.x;
    const int n0   = blockIdx.y * 128;
    const int tid  = threadIdx.x;
    const int lane = tid & 63;
    const int wv   = tid >> 6;           // 0..3
    const int cat  = cat_ids[b];

    const int mw = (wv & 1) * 32;        // wave t offset
    const int nw = (wv >> 1) * 64;       // wave n offset (within 128 tile)
    const int pw = (wv >> 1) * 4;        // wave n16-tile offset
    const int l15 = lane & 15;
    const int l4  = lane >> 4;

    const bf16_t* xb = xin + (size_t)b * (size_t)NT * KDIM;
    const float*  Wb = W + (size_t)cat * KDIM * NH + n0;

    f32x4 acc[2][4];
    #pragma unroll
    for (int nf = 0; nf < 4; ++nf) {
        float bv = bias[(size_t)cat * NH + n0 + nw + nf * 16 + l15];
        acc[0][nf] = (f32x4){bv, bv, bv, bv};
        acc[1][nf] = acc[0][nf];
    }

    // lane base for tr reads: group g=l>>4 -> k-tile pair 2g (stride 1024 B each)
    const unsigned wbase = (unsigned)(unsigned long long)&wsm[0];
    const unsigned laneB = wbase + (unsigned)(l4 * 2048 + l15 * 8);

    for (int kc = 0; kc < KDIM / 64; ++kc) {
        const bf16_t* xsrc = xb + kc * 64;
        const float*  Wp   = Wb + (size_t)(kc * 64) * NH;

        __syncthreads();   // prior-iter LDS reads done before overwrite

        // stage x chunk: [64t][64k] bf16, 512 x uint4
        #pragma unroll
        for (int p = 0; p < 2; ++p) {
            int id = tid + p * 256;
            int t  = id >> 3;
            int k8 = id & 7;
            uint4 v = *(const uint4*)(xsrc + (size_t)t * KDIM + k8 * 8);
            int off = (t * 128 + k8 * 16) ^ ((t & 7) << 4);
            *(uint4*)(xs + off) = v;
        }
        // stage W chunk: thread covers (k, 8-n octet) -> one ds_write_b128
        #pragma unroll
        for (int p = 0; p < 4; ++p) {
            int id  = tid + p * 256;      // 0..1023
            int k   = id >> 4;            // 0..63
            int oct = id & 15;            // 0..15 (n = oct*8)
            const float* src = Wp + (size_t)k * NH + oct * 8;
            float4 w0 = *(const float4*)(src);
            float4 w1 = *(const float4*)(src + 4);
            uint4 pk;
            pk.x = cvt2(w0.x, w0.y);
            pk.y = cvt2(w0.z, w0.w);
            pk.z = cvt2(w1.x, w1.y);
            pk.w = cvt2(w1.z, w1.w);
            int off = ((k >> 2) * 8 + (oct >> 1)) * 128 + (k & 3) * 32 + (oct & 1) * 16;
            *(uint4*)(wsm + off) = pk;
        }
        __syncthreads();

        #pragma unroll
        for (int ks = 0; ks < 2; ++ks) {
            // A frags from xs (proven r2 path)
            bf16x8 af[2];
            #pragma unroll
            for (int m = 0; m < 2; ++m) {
                int row = mw + m * 16 + l15;
                int off = (row * 128 + ks * 64 + l4 * 16) ^ ((row & 7) << 4);
                af[m] = *(const bf16x8*)(xs + off);
            }
            // B frags via hardware transpose read: lane gets
            // W[k = ks*32 + g*8 + j][n = 16*(pw+nf) + l15], j=0..7
            bf16x8 bfr[4];
            #pragma unroll
            for (int nf = 0; nf < 4; ++nf) {
                unsigned a = laneB + (unsigned)(ks * 8192 + (pw + nf) * 128);
                s16x4 lo, hi;
                asm volatile("ds_read_b64_tr_b16 %0, %1" : "=v"(lo) : "v"(a));
                asm volatile("ds_read_b64_tr_b16 %0, %1 offset:1024" : "=v"(hi) : "v"(a));
                bfr[nf] = __builtin_shufflevector(lo, hi, 0, 1, 2, 3, 4, 5, 6, 7);
            }
            // rule 18: drain asm ds reads and pin MFMAs after the wait
            asm volatile("s_waitcnt lgkmcnt(0)" ::: "memory");
            __builtin_amdgcn_sched_barrier(0);
            #pragma unroll
            for (int m = 0; m < 2; ++m)
                #pragma unroll
                for (int nf = 0; nf < 4; ++nf)
                    acc[m][nf] = __builtin_amdgcn_mfma_f32_16x16x32_bf16(
                        af[m], bfr[nf], acc[m][nf], 0, 0, 0);
        }
    }

    // epilogue: C/D layout col = lane&15, row = (lane>>4)*4 + reg  [m89/m91]
    #pragma unroll
    for (int m = 0; m < 2; ++m) {
        #pragma unroll
        for (int nf = 0; nf < 4; ++nf) {
            int col = n0 + nw + nf * 16 + l15;
            #pragma unroll
            for (int r = 0; r < 4; ++r) {
                int row = mw + m * 16 + l4 * 4 + r;
                float h = acc[m][nf][r];
                if (SWISH) h = h / (1.0f + __expf(-h));
                if constexpr (sizeof(OutT) == 2) {
                    out[((size_t)b * NT + row) * NH + col] = (OutT)f32_to_bf16(h);
                } else {
                    out[((size_t)b * NT + row) * NH + col] = h;
                }
            }
        }
    }
}

extern "C" void kernel_launch(void* const* d_in, const int* in_sizes, int n_in,
                              void* d_out, int out_size, void* d_ws, size_t ws_size,
                              hipStream_t stream) {
    const float* actions   = (const float*)d_in[0];
    const float* W1        = (const float*)d_in[1];
    const float* b1        = (const float*)d_in[2];
    const float* W2        = (const float*)d_in[3];
    const float* b2        = (const float*)d_in[4];
    const float* W3        = (const float*)d_in[5];
    const float* b3        = (const float*)d_in[6];
    const int*   timesteps = (const int*)d_in[7];
    const int*   cat_ids   = (const int*)d_in[8];
    float* out = (float*)d_out;

    // ws: x bf16 [B][T][2H] (16 MB) then y bf16 [B][T][H] (8 MB)
    bf16_t* x = (bf16_t*)d_ws;
    bf16_t* y = x + (size_t)NB * NT * K2DIM;

    k1_embed<<<dim3(NB, NH / 64), 256, 0, stream>>>(actions, W1, b1, timesteps, cat_ids, x);
    gemm_mfma<K2DIM, true,  bf16_t><<<dim3(NB, NH / 128), 256, 0, stream>>>(x, W2, b2, cat_ids, y);
    gemm_mfma<NH,    false, float ><<<dim3(NB, NH / 128), 256, 0, stream>>>(y, W3, b3, cat_ids, out);
}